// Round 11
// baseline (456.412 us; speedup 1.0000x reference)
//
#include <hip/hip_runtime.h>
#include <math.h>

typedef __attribute__((ext_vector_type(8))) short short8;
typedef __attribute__((ext_vector_type(4))) float f32x4;

static __device__ __forceinline__ unsigned short f2bf(float f) {
  union { float f; unsigned int u; } x; x.f = f;
  unsigned int r = x.u + 0x7fffu + ((x.u >> 16) & 1u);  // RNE
  return (unsigned short)(r >> 16);
}
static __device__ __forceinline__ float bf2f(unsigned int u) {
  union { unsigned int u; float f; } x; x.u = u << 16; return x.f;
}

// ---------------------------------------------------------------------------
// Block 0: int64-vs-int32 edge_index detection (OR of odd words of first
// 8192 elems; int64 => hi words zero => flag==0). ALL blocks: zero deg[padN]
// (replaces the hipMemsetAsync dispatch).
__global__ void k_flag(const unsigned int* __restrict__ w, int nSample,
                       unsigned int* __restrict__ flag,
                       int* __restrict__ deg, int padN) {
  // zero deg (int4 grid-stride)
  int4* d4 = (int4*)deg;
  int n4 = padN >> 2;
  for (int i = blockIdx.x * 256 + threadIdx.x; i < n4; i += gridDim.x * 256)
    d4[i] = make_int4(0, 0, 0, 0);
  if (blockIdx.x != 0) return;
  __shared__ unsigned int red[256];
  unsigned int v = 0;
  for (int i = threadIdx.x; i < nSample; i += 256) v |= w[2 * i + 1];
  red[threadIdx.x] = v;
  __syncthreads();
  for (int s = 128; s > 0; s >>= 1) {
    if (threadIdx.x < s) red[threadIdx.x] |= red[threadIdx.x + s];
    __syncthreads();
  }
  if (threadIdx.x == 0) flag[0] = red[0];  // nonzero => int32 layout
}

// Decode + degree count + PER-EDGE RANK (atomic return; atomic-free fill
// downstream). Also converts eattr f32 -> bf16: this kernel is atomic-
// latency-bound (VALUBusy ~0), so the streaming conversion rides free and
// k_edge3's A-fragment becomes a single 16B load.
__global__ void k_decode(const unsigned int* __restrict__ w,
                         const unsigned int* __restrict__ flag, int E,
                         const float4* __restrict__ ef,
                         uint2* __restrict__ eb,
                         int* __restrict__ src, int* __restrict__ tgt,
                         int* __restrict__ posin, int* __restrict__ deg) {
  int gid = blockIdx.x * 256 + threadIdx.x;
  int stride = gridDim.x * 256;
  // eattr conversion: E*4 float4s -> uint2 (4 bf16)
  for (int i = gid; i < E * 4; i += stride) {
    float4 v = ef[i];
    uint2 pk;
    pk.x = (unsigned int)f2bf(v.x) | ((unsigned int)f2bf(v.y) << 16);
    pk.y = (unsigned int)f2bf(v.z) | ((unsigned int)f2bf(v.w) << 16);
    eb[i] = pk;
  }
  int e = gid;
  if (e >= E) return;
  int s, t;
  if (flag[0]) { s = (int)w[e]; t = (int)w[E + e]; }
  else         { s = (int)w[2 * e]; t = (int)w[2 * (E + e)]; }
  src[e] = s;
  tgt[e] = t;
  posin[e] = atomicAdd(deg + t, 1);
}

// ---------------------------------------------------------------------------
// Hierarchical exclusive scan of deg[padN] (padN multiple of 2048, pad=0).
__global__ __launch_bounds__(256) void k_scan1(const int* __restrict__ deg,
                                               int* __restrict__ bsum) {
  __shared__ int wsum[4];
  const int tid = threadIdx.x, lane = tid & 63, wid = tid >> 6;
  const int base = blockIdx.x * 2048 + tid * 8;
  int4 v0 = *(const int4*)(deg + base);
  int4 v1 = *(const int4*)(deg + base + 4);
  int s = v0.x + v0.y + v0.z + v0.w + v1.x + v1.y + v1.z + v1.w;
#pragma unroll
  for (int off = 1; off < 64; off <<= 1) s += __shfl_xor(s, off, 64);
  if (lane == 0) wsum[wid] = s;
  __syncthreads();
  if (tid == 0) bsum[blockIdx.x] = wsum[0] + wsum[1] + wsum[2] + wsum[3];
}

__global__ void k_scan2(const int* __restrict__ bsum, int* __restrict__ boff,
                        int nB) {
  int lane = threadIdx.x;
  int v = (lane < nB) ? bsum[lane] : 0;
  int incl = v;
#pragma unroll
  for (int off = 1; off < 64; off <<= 1) {
    int t = __shfl_up(incl, off, 64);
    if (lane >= off) incl += t;
  }
  if (lane < nB) boff[lane] = incl - v;
}

__global__ __launch_bounds__(256) void k_scan3(const int* __restrict__ deg,
                                               const int* __restrict__ boff,
                                               int* __restrict__ rowptr) {
  __shared__ int wsum[4];
  const int tid = threadIdx.x, lane = tid & 63, wid = tid >> 6;
  const int base = blockIdx.x * 2048 + tid * 8;
  int4 v0 = *(const int4*)(deg + base);
  int4 v1 = *(const int4*)(deg + base + 4);
  int e[8] = {v0.x, v0.y, v0.z, v0.w, v1.x, v1.y, v1.z, v1.w};
  int s = e[0] + e[1] + e[2] + e[3] + e[4] + e[5] + e[6] + e[7];
  int incl = s;
#pragma unroll
  for (int off = 1; off < 64; off <<= 1) {
    int t = __shfl_up(incl, off, 64);
    if (lane >= off) incl += t;
  }
  if (lane == 63) wsum[wid] = incl;
  __syncthreads();
  int run = boff[blockIdx.x] + (incl - s);
  for (int w = 0; w < wid; ++w) run += wsum[w];
  int o[8];
#pragma unroll
  for (int i = 0; i < 8; ++i) { o[i] = run; run += e[i]; }
  *(int4*)(rowptr + base) = make_int4(o[0], o[1], o[2], o[3]);
  *(int4*)(rowptr + base + 4) = make_int4(o[4], o[5], o[6], o[7]);
}

// Atomic-free CSR fill: position precomputed as rowptr[tgt] + rank.
__global__ void k_fill(const int* __restrict__ src, const int* __restrict__ tgt,
                       const int* __restrict__ posin,
                       const int* __restrict__ rowptr,
                       int* __restrict__ csrc, int E) {
  int e = blockIdx.x * 256 + threadIdx.x;
  if (e >= E) return;
  csrc[rowptr[tgt[e]] + posin[e]] = src[e];
}

// ---------------------------------------------------------------------------
// Merged weight prep (was k_prep + 2x k_prep2; saves 2 dispatches).
// Block 0: W25T=(We2@Wo1)^T bf16[n][k]; We1T bf16[n][k] K-pad 16->32;
//          Wo1T bf16[n][k]; cvec = be2@Wo1 + bo1.
// Blocks 1..64:  WnT0[n][k] bf16 over [Wl0|Wr0] (K=128).
// Blocks 65..96: WnT1[n][k] bf16 over [Wl1|Wr1] (K=64).
__global__ __launch_bounds__(256) void k_prepall(
    const float* __restrict__ We2, const float* __restrict__ Wo1,
    const float* __restrict__ be2, const float* __restrict__ bo1,
    const float* __restrict__ We1,
    const float* __restrict__ Wl0, const float* __restrict__ Wr0,
    const float* __restrict__ Wl1, const float* __restrict__ Wr1,
    unsigned short* __restrict__ W25T, unsigned short* __restrict__ We1T,
    unsigned short* __restrict__ Wo1T, float* __restrict__ cvec,
    unsigned short* __restrict__ WnT0, unsigned short* __restrict__ WnT1) {
  const int tid = threadIdx.x;
  if (blockIdx.x == 0) {
    __shared__ float sA[4096];  // We2
    __shared__ float sB[4096];  // Wo1
    for (int i = tid; i < 1024; i += 256) {
      *(float4*)&sA[i * 4] = *(const float4*)(We2 + i * 4);
      *(float4*)&sB[i * 4] = *(const float4*)(Wo1 + i * 4);
    }
    __syncthreads();
    for (int idx = tid; idx < 4096; idx += 256) {
      int n = idx >> 6, k = idx & 63;
      float s = 0.f;
#pragma unroll 8
      for (int mm = 0; mm < 64; ++mm) s = fmaf(sA[k * 64 + mm], sB[mm * 64 + n], s);
      W25T[idx] = f2bf(s);
      Wo1T[idx] = f2bf(sB[k * 64 + n]);
    }
    for (int idx = tid; idx < 2048; idx += 256) {
      int n = idx >> 5, k = idx & 31;
      We1T[n * 32 + k] = (k < 16) ? f2bf(We1[k * 64 + n]) : (unsigned short)0;
    }
    if (tid < 64) {
      float s = bo1[tid];
#pragma unroll 8
      for (int mm = 0; mm < 64; ++mm) s = fmaf(be2[mm], sB[mm * 64 + tid], s);
      cvec[tid] = s;
    }
  } else if (blockIdx.x <= 64) {
    int idx = (blockIdx.x - 1) * 256 + tid;      // 128*128 = 16384
    int n = idx >> 7, k = idx & 127;
    float v = (n < 64) ? Wl0[(size_t)k * 64 + n] : Wr0[(size_t)k * 64 + (n - 64)];
    WnT0[idx] = f2bf(v);
  } else {
    int idx = (blockIdx.x - 65) * 256 + tid;     // 128*64 = 8192
    int n = idx >> 6, k = idx & 63;
    float v = (n < 64) ? Wl1[(size_t)k * 64 + n] : Wr1[(size_t)k * 64 + (n - 64)];
    WnT1[idx] = f2bf(v);
  }
}

// MFMA node GEMM, bf16 output. BF16IN: X is bf16 [N,K] else f32 [N,K].
// NTILES=2: cols [W0|W1]=128, wave wv covers cols wv*32..+32, writes Y0/Y1.
// NTILES=1: 64 cols, wave wv covers cols wv*16..+16, writes Y0.
// MFMA layouts (gfx950, verified): A[m=lane&15][k=(lane>>4)*8+j],
// B[k][n=lane&15] (frag = WnT[n][k] contig in k), C/D col=lane&15,
// row=(lane>>4)*4+reg.
template <int K, bool BF16IN, int NTILES>
__global__ __launch_bounds__(256) void k_ngemm(
    const void* __restrict__ Xv, const unsigned short* __restrict__ WnT,
    unsigned short* __restrict__ Y0, unsigned short* __restrict__ Y1, int N) {
  constexpr int STR = K + 8;   // +16B pad: 2-way banks max, b128 aligned
  constexpr int NC = K / 32;
  __shared__ unsigned short sX[64 * STR];
  const int tid = threadIdx.x;
  const int wv = tid >> 6, lane = tid & 63;
  const int m = lane & 15, q = lane >> 4;
  const int row0 = blockIdx.x * 64;

  short8 bB[NTILES][NC];
#pragma unroll
  for (int ct = 0; ct < NTILES; ++ct)
#pragma unroll
    for (int c = 0; c < NC; ++c) {
      int n = (NTILES == 2) ? (wv * 32 + ct * 16 + m) : (wv * 16 + m);
      bB[ct][c] = *(const short8*)(WnT + (size_t)n * K + c * 32 + q * 8);
    }

#pragma unroll
  for (int i = 0; i < K / 16; ++i) {
    int f = tid + 256 * i;
    int r = f / (K / 4);
    int c4 = f % (K / 4);
    int rr = row0 + r; if (rr >= N) rr = N - 1;
    uint2 pk;
    if constexpr (BF16IN) {
      pk = *(const uint2*)((const unsigned short*)Xv + (size_t)rr * K + c4 * 4);
    } else {
      float4 v = *(const float4*)((const float*)Xv + (size_t)rr * K + c4 * 4);
      pk.x = (unsigned int)f2bf(v.x) | ((unsigned int)f2bf(v.y) << 16);
      pk.y = (unsigned int)f2bf(v.z) | ((unsigned int)f2bf(v.w) << 16);
    }
    *(uint2*)(sX + r * STR + c4 * 4) = pk;
  }
  __syncthreads();

  f32x4 acc[4][NTILES];
#pragma unroll
  for (int rt = 0; rt < 4; ++rt)
#pragma unroll
    for (int ct = 0; ct < NTILES; ++ct)
#pragma unroll
      for (int r = 0; r < 4; ++r) acc[rt][ct][r] = 0.f;

#pragma unroll
  for (int c = 0; c < NC; ++c) {
    short8 a[4];
#pragma unroll
    for (int rt = 0; rt < 4; ++rt)
      a[rt] = *(const short8*)(sX + (rt * 16 + m) * STR + c * 32 + q * 8);
#pragma unroll
    for (int rt = 0; rt < 4; ++rt)
#pragma unroll
      for (int ct = 0; ct < NTILES; ++ct)
        acc[rt][ct] = __builtin_amdgcn_mfma_f32_16x16x32_bf16(a[rt], bB[ct][c], acc[rt][ct], 0, 0, 0);
  }

#pragma unroll
  for (int rt = 0; rt < 4; ++rt)
#pragma unroll
    for (int ct = 0; ct < NTILES; ++ct) {
      unsigned short* Yw;
      int n;
      if constexpr (NTILES == 2) {
        Yw = (wv < 2) ? Y0 : Y1;
        n = (wv & 1) * 32 + ct * 16 + m;
      } else {
        Yw = Y0;
        n = wv * 16 + m;
      }
#pragma unroll
      for (int reg = 0; reg < 4; ++reg) {
        int row = row0 + rt * 16 + q * 4 + reg;
        if (row < N) Yw[(size_t)row * 64 + n] = f2bf(acc[rt][ct][reg]);
      }
    }
}

// CSR aggregate fused with epilogue: H = relu(sum/deg + bias + Yr).
// All node features bf16 (rows 128B); f32 accumulation.
__global__ __launch_bounds__(256) void k_agg(
    const unsigned short* __restrict__ Y, const int* __restrict__ rowptr,
    const int* __restrict__ csrc, const float* __restrict__ bias,
    const unsigned short* __restrict__ Yr, unsigned short* __restrict__ H,
    int N) {
  int node = (blockIdx.x * 256 + threadIdx.x) >> 6;
  if (node >= N) return;
  const int lane = threadIdx.x & 63;
  const int c4 = lane & 15, rr = lane >> 4;
  int beg = rowptr[node], end = rowptr[node + 1];
  float a0 = 0.f, a1 = 0.f, a2 = 0.f, a3 = 0.f;
  float b0 = 0.f, b1 = 0.f, b2 = 0.f, b3 = 0.f;
  for (int e = beg; e < end; e += 8) {
    int e0 = e + rr, e1 = e + 4 + rr;
    if (e0 < end) {
      int s = csrc[e0];
      uint2 v = *(const uint2*)(Y + (size_t)s * 64 + c4 * 4);
      a0 += bf2f(v.x & 0xffffu); a1 += bf2f(v.x >> 16);
      a2 += bf2f(v.y & 0xffffu); a3 += bf2f(v.y >> 16);
    }
    if (e1 < end) {
      int s = csrc[e1];
      uint2 v = *(const uint2*)(Y + (size_t)s * 64 + c4 * 4);
      b0 += bf2f(v.x & 0xffffu); b1 += bf2f(v.x >> 16);
      b2 += bf2f(v.y & 0xffffu); b3 += bf2f(v.y >> 16);
    }
  }
  a0 += b0; a1 += b1; a2 += b2; a3 += b3;
#pragma unroll
  for (int msk = 16; msk <= 32; msk <<= 1) {
    a0 += __shfl_xor(a0, msk, 64);
    a1 += __shfl_xor(a1, msk, 64);
    a2 += __shfl_xor(a2, msk, 64);
    a3 += __shfl_xor(a3, msk, 64);
  }
  if (rr == 0) {
    float cdeg = (float)(end - beg);
    if (cdeg < 1.f) cdeg = 1.f;
    float inv = 1.f / cdeg;
    float4 bv = *(const float4*)(bias + c4 * 4);
    uint2 yv = *(const uint2*)(Yr + (size_t)node * 64 + c4 * 4);
    float o0 = fmaxf(a0 * inv + bv.x + bf2f(yv.x & 0xffffu), 0.f);
    float o1 = fmaxf(a1 * inv + bv.y + bf2f(yv.x >> 16), 0.f);
    float o2 = fmaxf(a2 * inv + bv.z + bf2f(yv.y & 0xffffu), 0.f);
    float o3 = fmaxf(a3 * inv + bv.w + bf2f(yv.y >> 16), 0.f);
    uint2 pk;
    pk.x = (unsigned int)f2bf(o0) | ((unsigned int)f2bf(o1) << 16);
    pk.y = (unsigned int)f2bf(o2) | ((unsigned int)f2bf(o3) << 16);
    *(uint2*)(H + (size_t)node * 64 + c4 * 4) = pk;
  }
}

// ---------------------------------------------------------------------------
// MFMA edge pipeline v3: EA is pre-converted bf16 (EAb, 32B rows) so the
// A-fragment is ONE 16B load (q<2 lanes); G row gathers coalesced via quads,
// C-layout redistribution through per-wave f32 LDS (<=2-way banks).
// MFMA layouts (gfx950, verified): A[m=lane&15][k=(lane>>4)*8+j],
// B[k=(lane>>4)*8+j][n=lane&15], C/D col=lane&15, row=(lane>>4)*4+reg.
#define T1_STRIDE 72
#define G_STRIDE 68
__global__ __launch_bounds__(256) void k_edge3(
    const unsigned short* __restrict__ EAb, const int* __restrict__ src,
    const int* __restrict__ tgt, const unsigned short* __restrict__ Gb,
    const unsigned short* __restrict__ We1T,
    const unsigned short* __restrict__ W25T,
    const float* __restrict__ cvec, const float* __restrict__ be1,
    const float* __restrict__ Wo2, const float* __restrict__ bo2,
    float* __restrict__ out, int E, int nT, int nWaves) {
  __shared__ unsigned short sT1a[4][16 * T1_STRIDE];
  __shared__ float sGa[4][16 * G_STRIDE];
  const int tid = threadIdx.x;
  const int wid = tid >> 6, lane = tid & 63;
  const int m = lane & 15, q = lane >> 4;
  unsigned short* sT1 = sT1a[wid];
  float* sG = sGa[wid];

  short8 bWe1[4], bW25[4][2];
  float cv[4], wo2v[4], be1v[4];
#pragma unroll
  for (int nt = 0; nt < 4; ++nt) {
    int n = nt * 16 + m;
    bWe1[nt] = *(const short8*)(We1T + n * 32 + q * 8);
    bW25[nt][0] = *(const short8*)(W25T + n * 64 + q * 8);
    bW25[nt][1] = *(const short8*)(W25T + n * 64 + 32 + q * 8);
    cv[nt] = cvec[n];
    wo2v[nt] = Wo2[n];
    be1v[nt] = be1[n];
  }
  const float b_out = bo2[0];
  const short8 zfrag = {};

  int t = blockIdx.x * 4 + wid;
  if (t >= nT) return;
  int il = t * 16 + m; if (il >= E) il = E - 1;
  int my_idx = (lane < 16) ? src[il] : ((lane < 32) ? tgt[il] : 0);

  while (true) {
    const int base = t * 16;
    const int tn = t + nWaves;
    const bool last = (tn >= nT);
    const int tc = last ? t : tn;

    int il_n = tc * 16 + m; if (il_n >= E) il_n = E - 1;
    int idx_n = (lane < 16) ? src[il_n] : ((lane < 32) ? tgt[il_n] : 0);

    // coalesced G row gathers: quad q owns edges q*4..q*4+3
    int rs[4], rt[4];
#pragma unroll
    for (int r = 0; r < 4; ++r) {
      rs[r] = __shfl(my_idx, q * 4 + r, 64);
      rt[r] = __shfl(my_idx, 16 + q * 4 + r, 64);
    }
    uint2 sv[4], tv[4];
#pragma unroll
    for (int r = 0; r < 4; ++r) {
      sv[r] = *(const uint2*)(Gb + (size_t)rs[r] * 64 + m * 4);
      tv[r] = *(const uint2*)(Gb + (size_t)rt[r] * 64 + m * 4);
    }

    // EA A-fragment: single 16B bf16 load (K-pad lanes q>=2 are zero)
    int er = base + m; if (er >= E) er = E - 1;
    short8 aEA = zfrag;
    if (q < 2) aEA = *(const short8*)(EAb + (size_t)er * 16 + (q & 1) * 8);

    // MFMA1: t1 = relu(EA @ We1 + be1)
    f32x4 t1[4];
#pragma unroll
    for (int nt = 0; nt < 4; ++nt) {
      f32x4 cinit; cinit[0] = be1v[nt]; cinit[1] = be1v[nt];
      cinit[2] = be1v[nt]; cinit[3] = be1v[nt];
      t1[nt] = __builtin_amdgcn_mfma_f32_16x16x32_bf16(aEA, bWe1[nt], cinit, 0, 0, 0);
    }
#pragma unroll
    for (int nt = 0; nt < 4; ++nt)
#pragma unroll
      for (int r = 0; r < 4; ++r)
        sT1[(q * 4 + r) * T1_STRIDE + nt * 16 + m] = f2bf(fmaxf(t1[nt][r], 0.f));
    short8 aT0 = *(short8*)(sT1 + m * T1_STRIDE + q * 8);
    short8 aT1 = *(short8*)(sT1 + m * T1_STRIDE + 32 + q * 8);

    // Gsum -> sG (f32): lane holds feats 4m..4m+3 of edge q*4+r
#pragma unroll
    for (int r = 0; r < 4; ++r) {
      f32x4 g;
      g[0] = bf2f(sv[r].x & 0xffffu) + bf2f(tv[r].x & 0xffffu);
      g[1] = bf2f(sv[r].x >> 16)     + bf2f(tv[r].x >> 16);
      g[2] = bf2f(sv[r].y & 0xffffu) + bf2f(tv[r].y & 0xffffu);
      g[3] = bf2f(sv[r].y >> 16)     + bf2f(tv[r].y >> 16);
      *(f32x4*)(sG + (q * 4 + r) * G_STRIDE + m * 4) = g;
    }

    // acc init (C layout) + MFMA2
    f32x4 acc[4];
#pragma unroll
    for (int nt = 0; nt < 4; ++nt)
#pragma unroll
      for (int r = 0; r < 4; ++r)
        acc[nt][r] = cv[nt] + sG[(q * 4 + r) * G_STRIDE + nt * 16 + m];
#pragma unroll
    for (int nt = 0; nt < 4; ++nt) {
      acc[nt] = __builtin_amdgcn_mfma_f32_16x16x32_bf16(aT0, bW25[nt][0], acc[nt], 0, 0, 0);
      acc[nt] = __builtin_amdgcn_mfma_f32_16x16x32_bf16(aT1, bW25[nt][1], acc[nt], 0, 0, 0);
    }

    // epilogue
    float p[4];
#pragma unroll
    for (int r = 0; r < 4; ++r) {
      p[r] = fmaxf(acc[0][r], 0.f) * wo2v[0] + fmaxf(acc[1][r], 0.f) * wo2v[1] +
             fmaxf(acc[2][r], 0.f) * wo2v[2] + fmaxf(acc[3][r], 0.f) * wo2v[3];
    }
#pragma unroll
    for (int msk = 1; msk <= 8; msk <<= 1) {
#pragma unroll
      for (int r = 0; r < 4; ++r) p[r] += __shfl_xor(p[r], msk, 64);
    }
    if (m == 0) {
#pragma unroll
      for (int r = 0; r < 4; ++r) {
        int row = base + q * 4 + r;
        if (row < E) out[row] = 1.f / (1.f + __expf(-(p[r] + b_out)));
      }
    }

    if (last) break;
    t = tn; my_idx = idx_n;
  }
}

// ---------------------------------------------------------------------------
extern "C" void kernel_launch(void* const* d_in, const int* in_sizes, int n_in,
                              void* d_out, int out_size, void* d_ws, size_t ws_size,
                              hipStream_t stream) {
  const float* x     = (const float*)d_in[0];
  const unsigned int* eidx = (const unsigned int*)d_in[1];
  const float* eattr = (const float*)d_in[2];
  const float* We1 = (const float*)d_in[3];
  const float* be1 = (const float*)d_in[4];
  const float* We2 = (const float*)d_in[5];
  const float* be2 = (const float*)d_in[6];
  const float* Wl0 = (const float*)d_in[7];
  const float* bl0 = (const float*)d_in[8];
  const float* Wr0 = (const float*)d_in[9];
  const float* Wl1 = (const float*)d_in[10];
  const float* bl1 = (const float*)d_in[11];
  const float* Wr1 = (const float*)d_in[12];
  const float* Wo1 = (const float*)d_in[13];
  const float* bo1 = (const float*)d_in[14];
  const float* Wo2 = (const float*)d_in[15];
  const float* bo2 = (const float*)d_in[16];

  const int N = in_sizes[0] / 128;   // 100000
  const int E = in_sizes[2] / 16;    // 1000000
  const int padN = (N + 2047) & ~2047;
  const int nB = padN / 2048;
  float* out = (float*)d_out;

  char* ws = (char*)d_ws;
  size_t off = 0;
  auto alloc = [&](size_t bytes) {
    char* p = ws + off;
    off += (bytes + 255) & ~(size_t)255;
    return p;
  };
  unsigned int* flag = (unsigned int*)alloc(256);
  int* src    = (int*)alloc((size_t)E * 4);
  int* tgt    = (int*)alloc((size_t)E * 4);
  int* posin  = (int*)alloc((size_t)E * 4);
  int* deg    = (int*)alloc((size_t)padN * 4);
  int* rowptr = (int*)alloc((size_t)(padN + 64) * 4);
  int* bsum   = (int*)alloc(64 * 4);
  int* boff   = (int*)alloc(64 * 4);
  int* csrc   = (int*)alloc((size_t)E * 4);
  unsigned short* EAb = (unsigned short*)alloc((size_t)E * 16 * 2);
  unsigned short* Hb = (unsigned short*)alloc((size_t)N * 64 * 2);
  unsigned short* Yl = (unsigned short*)alloc((size_t)N * 64 * 2);
  unsigned short* Yr = (unsigned short*)alloc((size_t)N * 64 * 2);
  unsigned short* Gb = (unsigned short*)alloc((size_t)N * 64 * 2);
  unsigned short* W25T = (unsigned short*)alloc(64 * 64 * 2);
  unsigned short* We1T = (unsigned short*)alloc(64 * 32 * 2);
  unsigned short* Wo1T = (unsigned short*)alloc(64 * 64 * 2);
  unsigned short* WnT0 = (unsigned short*)alloc(128 * 128 * 2);
  unsigned short* WnT1 = (unsigned short*)alloc(128 * 64 * 2);
  float* cvec = (float*)alloc(64 * 4);
  (void)ws_size; (void)n_in; (void)out_size;

  k_flag<<<64, 256, 0, stream>>>(eidx, 8192, flag, deg, padN);
  k_decode<<<(E + 255) / 256, 256, 0, stream>>>(
      eidx, flag, E, (const float4*)eattr, (uint2*)EAb, src, tgt, posin, deg);
  k_scan1<<<nB, 256, 0, stream>>>(deg, bsum);
  k_scan2<<<1, 64, 0, stream>>>(bsum, boff, nB);
  k_scan3<<<nB, 256, 0, stream>>>(deg, boff, rowptr);
  k_fill<<<(E + 255) / 256, 256, 0, stream>>>(src, tgt, posin, rowptr, csrc, E);
  k_prepall<<<97, 256, 0, stream>>>(We2, Wo1, be2, bo1, We1, Wl0, Wr0, Wl1, Wr1,
                                    W25T, We1T, Wo1T, cvec, WnT0, WnT1);

  const int gB = (N + 63) / 64;
  // Layer 0 (project-then-aggregate: mean is linear) — MFMA, bf16 out
  k_ngemm<128, false, 2><<<gB, 256, 0, stream>>>(x, WnT0, Yl, Yr, N);
  k_agg<<<(N + 3) / 4, 256, 0, stream>>>(Yl, rowptr, csrc, bl0, Yr, Hb, N);

  // Layer 1 — MFMA, bf16 in/out
  k_ngemm<64, true, 2><<<gB, 256, 0, stream>>>(Hb, WnT1, Yl, Yr, N);
  k_agg<<<(N + 3) / 4, 256, 0, stream>>>(Yl, rowptr, csrc, bl1, Yr, Hb, N);

  // G = H2 @ Wo1 — MFMA, bf16 in/out
  k_ngemm<64, true, 1><<<gB, 256, 0, stream>>>(Hb, Wo1T, Gb, nullptr, N);

  // MFMA edge pipeline v3
  const int nT = (E + 15) / 16;
  const int blocks = 3072;
  k_edge3<<<blocks, 256, 0, stream>>>(EAb, src, tgt, Gb, We1T, W25T, cvec,
                                      be1, Wo2, bo2, out, E, nT, blocks * 4);
}

// Round 12
// 446.168 us; speedup vs baseline: 1.0230x; 1.0230x over previous
//
#include <hip/hip_runtime.h>
#include <math.h>

typedef __attribute__((ext_vector_type(8))) short short8;
typedef __attribute__((ext_vector_type(4))) float f32x4;

static __device__ __forceinline__ unsigned short f2bf(float f) {
  union { float f; unsigned int u; } x; x.f = f;
  unsigned int r = x.u + 0x7fffu + ((x.u >> 16) & 1u);  // RNE
  return (unsigned short)(r >> 16);
}
static __device__ __forceinline__ float bf2f(unsigned int u) {
  union { unsigned int u; float f; } x; x.u = u << 16; return x.f;
}

// ---------------------------------------------------------------------------
// Block 0: int64-vs-int32 edge_index detection. ALL blocks: zero deg[padN].
__global__ void k_flag(const unsigned int* __restrict__ w, int nSample,
                       unsigned int* __restrict__ flag,
                       int* __restrict__ deg, int padN) {
  int4* d4 = (int4*)deg;
  int n4 = padN >> 2;
  for (int i = blockIdx.x * 256 + threadIdx.x; i < n4; i += gridDim.x * 256)
    d4[i] = make_int4(0, 0, 0, 0);
  if (blockIdx.x != 0) return;
  __shared__ unsigned int red[256];
  unsigned int v = 0;
  for (int i = threadIdx.x; i < nSample; i += 256) v |= w[2 * i + 1];
  red[threadIdx.x] = v;
  __syncthreads();
  for (int s = 128; s > 0; s >>= 1) {
    if (threadIdx.x < s) red[threadIdx.x] |= red[threadIdx.x + s];
    __syncthreads();
  }
  if (threadIdx.x == 0) flag[0] = red[0];  // nonzero => int32 layout
}

// ---------------------------------------------------------------------------
// MEGA1: decode blocks (atomic-latency-bound) co-scheduled with weight-prep
// blocks (VALU/BW) in ONE dispatch so prep cost hides under atomic stalls.
//  blocks [0, nDec)        : decode + degree + per-edge rank
//  block  nDec + 0         : W25T/We1T/Wo1T/cvec (16 KB LDS: Wo1 only)
//  blocks nDec+1..nDec+64  : WnT0 (K=128 transpose->bf16)
//  blocks nDec+65..nDec+96 : WnT1 (K=64)
__global__ __launch_bounds__(256) void k_mega1(
    const unsigned int* __restrict__ w, const unsigned int* __restrict__ flag,
    int E, int nDec,
    int* __restrict__ src, int* __restrict__ tgt,
    int* __restrict__ posin, int* __restrict__ deg,
    const float* __restrict__ We2, const float* __restrict__ Wo1,
    const float* __restrict__ be2, const float* __restrict__ bo1,
    const float* __restrict__ We1,
    const float* __restrict__ Wl0, const float* __restrict__ Wr0,
    const float* __restrict__ Wl1, const float* __restrict__ Wr1,
    unsigned short* __restrict__ W25T, unsigned short* __restrict__ We1T,
    unsigned short* __restrict__ Wo1T, float* __restrict__ cvec,
    unsigned short* __restrict__ WnT0, unsigned short* __restrict__ WnT1) {
  __shared__ float sB[4096];  // used only by prep block 0 (Wo1)
  const int tid = threadIdx.x;
  if (blockIdx.x < nDec) {
    int e = blockIdx.x * 256 + tid;
    if (e >= E) return;
    int s, t;
    if (flag[0]) { s = (int)w[e]; t = (int)w[E + e]; }
    else         { s = (int)w[2 * e]; t = (int)w[2 * (E + e)]; }
    src[e] = s;
    tgt[e] = t;
    posin[e] = atomicAdd(deg + t, 1);
    return;
  }
  const int b = blockIdx.x - nDec;
  if (b == 0) {
    for (int i = tid; i < 1024; i += 256)
      *(float4*)&sB[i * 4] = *(const float4*)(Wo1 + i * 4);
    __syncthreads();
    // idx: k = idx>>6 (wave-uniform -> We2 row reads scalarize), n = idx&63
    for (int idx = tid; idx < 4096; idx += 256) {
      int k = idx >> 6, n = idx & 63;
      float s = 0.f;
#pragma unroll 8
      for (int mm = 0; mm < 64; ++mm) s = fmaf(We2[k * 64 + mm], sB[mm * 64 + n], s);
      W25T[n * 64 + k] = f2bf(s);
      Wo1T[n * 64 + k] = f2bf(sB[k * 64 + n]);
    }
    for (int idx = tid; idx < 2048; idx += 256) {
      int n = idx >> 5, k = idx & 31;
      We1T[n * 32 + k] = (k < 16) ? f2bf(We1[k * 64 + n]) : (unsigned short)0;
    }
    if (tid < 64) {
      float s = bo1[tid];
#pragma unroll 8
      for (int mm = 0; mm < 64; ++mm) s = fmaf(be2[mm], sB[mm * 64 + tid], s);
      cvec[tid] = s;
    }
  } else if (b <= 64) {
    int idx = (b - 1) * 256 + tid;               // 128*128 = 16384
    int n = idx >> 7, k = idx & 127;
    float v = (n < 64) ? Wl0[(size_t)k * 64 + n] : Wr0[(size_t)k * 64 + (n - 64)];
    WnT0[idx] = f2bf(v);
  } else {
    int idx = (b - 65) * 256 + tid;              // 128*64 = 8192
    int n = idx >> 6, k = idx & 63;
    float v = (n < 64) ? Wl1[(size_t)k * 64 + n] : Wr1[(size_t)k * 64 + (n - 64)];
    WnT1[idx] = f2bf(v);
  }
}

// ---------------------------------------------------------------------------
// Hierarchical exclusive scan of deg[padN] (padN multiple of 2048, pad=0).
__global__ __launch_bounds__(256) void k_scan1(const int* __restrict__ deg,
                                               int* __restrict__ bsum) {
  __shared__ int wsum[4];
  const int tid = threadIdx.x, lane = tid & 63, wid = tid >> 6;
  const int base = blockIdx.x * 2048 + tid * 8;
  int4 v0 = *(const int4*)(deg + base);
  int4 v1 = *(const int4*)(deg + base + 4);
  int s = v0.x + v0.y + v0.z + v0.w + v1.x + v1.y + v1.z + v1.w;
#pragma unroll
  for (int off = 1; off < 64; off <<= 1) s += __shfl_xor(s, off, 64);
  if (lane == 0) wsum[wid] = s;
  __syncthreads();
  if (tid == 0) bsum[blockIdx.x] = wsum[0] + wsum[1] + wsum[2] + wsum[3];
}

__global__ void k_scan2(const int* __restrict__ bsum, int* __restrict__ boff,
                        int nB) {
  int lane = threadIdx.x;
  int v = (lane < nB) ? bsum[lane] : 0;
  int incl = v;
#pragma unroll
  for (int off = 1; off < 64; off <<= 1) {
    int t = __shfl_up(incl, off, 64);
    if (lane >= off) incl += t;
  }
  if (lane < nB) boff[lane] = incl - v;
}

__global__ __launch_bounds__(256) void k_scan3(const int* __restrict__ deg,
                                               const int* __restrict__ boff,
                                               int* __restrict__ rowptr) {
  __shared__ int wsum[4];
  const int tid = threadIdx.x, lane = tid & 63, wid = tid >> 6;
  const int base = blockIdx.x * 2048 + tid * 8;
  int4 v0 = *(const int4*)(deg + base);
  int4 v1 = *(const int4*)(deg + base + 4);
  int e[8] = {v0.x, v0.y, v0.z, v0.w, v1.x, v1.y, v1.z, v1.w};
  int s = e[0] + e[1] + e[2] + e[3] + e[4] + e[5] + e[6] + e[7];
  int incl = s;
#pragma unroll
  for (int off = 1; off < 64; off <<= 1) {
    int t = __shfl_up(incl, off, 64);
    if (lane >= off) incl += t;
  }
  if (lane == 63) wsum[wid] = incl;
  __syncthreads();
  int run = boff[blockIdx.x] + (incl - s);
  for (int w = 0; w < wid; ++w) run += wsum[w];
  int o[8];
#pragma unroll
  for (int i = 0; i < 8; ++i) { o[i] = run; run += e[i]; }
  *(int4*)(rowptr + base) = make_int4(o[0], o[1], o[2], o[3]);
  *(int4*)(rowptr + base + 4) = make_int4(o[4], o[5], o[6], o[7]);
}

// ---------------------------------------------------------------------------
// MFMA node GEMM body (device fn; shared by standalone and mega2 kernels).
// MFMA layouts (gfx950, verified): A[m=lane&15][k=(lane>>4)*8+j],
// B[k][n=lane&15], C/D col=lane&15, row=(lane>>4)*4+reg.
template <int K, bool BF16IN, int NTILES>
__device__ __forceinline__ void ngemm_body(
    const void* __restrict__ Xv, const unsigned short* __restrict__ WnT,
    unsigned short* __restrict__ Y0, unsigned short* __restrict__ Y1,
    int N, int blk) {
  constexpr int STR = K + 8;
  constexpr int NC = K / 32;
  __shared__ unsigned short sX[64 * STR];
  const int tid = threadIdx.x;
  const int wv = tid >> 6, lane = tid & 63;
  const int m = lane & 15, q = lane >> 4;
  const int row0 = blk * 64;

  short8 bB[NTILES][NC];
#pragma unroll
  for (int ct = 0; ct < NTILES; ++ct)
#pragma unroll
    for (int c = 0; c < NC; ++c) {
      int n = (NTILES == 2) ? (wv * 32 + ct * 16 + m) : (wv * 16 + m);
      bB[ct][c] = *(const short8*)(WnT + (size_t)n * K + c * 32 + q * 8);
    }

#pragma unroll
  for (int i = 0; i < K / 16; ++i) {
    int f = tid + 256 * i;
    int r = f / (K / 4);
    int c4 = f % (K / 4);
    int rr = row0 + r; if (rr >= N) rr = N - 1;
    uint2 pk;
    if constexpr (BF16IN) {
      pk = *(const uint2*)((const unsigned short*)Xv + (size_t)rr * K + c4 * 4);
    } else {
      float4 v = *(const float4*)((const float*)Xv + (size_t)rr * K + c4 * 4);
      pk.x = (unsigned int)f2bf(v.x) | ((unsigned int)f2bf(v.y) << 16);
      pk.y = (unsigned int)f2bf(v.z) | ((unsigned int)f2bf(v.w) << 16);
    }
    *(uint2*)(sX + r * STR + c4 * 4) = pk;
  }
  __syncthreads();

  f32x4 acc[4][NTILES];
#pragma unroll
  for (int rt = 0; rt < 4; ++rt)
#pragma unroll
    for (int ct = 0; ct < NTILES; ++ct)
#pragma unroll
      for (int r = 0; r < 4; ++r) acc[rt][ct][r] = 0.f;

#pragma unroll
  for (int c = 0; c < NC; ++c) {
    short8 a[4];
#pragma unroll
    for (int rt = 0; rt < 4; ++rt)
      a[rt] = *(const short8*)(sX + (rt * 16 + m) * STR + c * 32 + q * 8);
#pragma unroll
    for (int rt = 0; rt < 4; ++rt)
#pragma unroll
      for (int ct = 0; ct < NTILES; ++ct)
        acc[rt][ct] = __builtin_amdgcn_mfma_f32_16x16x32_bf16(a[rt], bB[ct][c], acc[rt][ct], 0, 0, 0);
  }

#pragma unroll
  for (int rt = 0; rt < 4; ++rt)
#pragma unroll
    for (int ct = 0; ct < NTILES; ++ct) {
      unsigned short* Yw;
      int n;
      if constexpr (NTILES == 2) {
        Yw = (wv < 2) ? Y0 : Y1;
        n = (wv & 1) * 32 + ct * 16 + m;
      } else {
        Yw = Y0;
        n = wv * 16 + m;
      }
#pragma unroll
      for (int reg = 0; reg < 4; ++reg) {
        int row = row0 + rt * 16 + q * 4 + reg;
        if (row < N) Yw[(size_t)row * 64 + n] = f2bf(acc[rt][ct][reg]);
      }
    }
}

template <int K, bool BF16IN, int NTILES>
__global__ __launch_bounds__(256) void k_ngemm(
    const void* __restrict__ Xv, const unsigned short* __restrict__ WnT,
    unsigned short* __restrict__ Y0, unsigned short* __restrict__ Y1, int N) {
  ngemm_body<K, BF16IN, NTILES>(Xv, WnT, Y0, Y1, N, blockIdx.x);
}

// MEGA2: ngemm<128> blocks (MFMA/BW) + atomic-free CSR-fill blocks
// (scatter-latency) in one dispatch.
__global__ __launch_bounds__(256) void k_mega2(
    const void* __restrict__ Xv, const unsigned short* __restrict__ WnT,
    unsigned short* __restrict__ Y0, unsigned short* __restrict__ Y1, int N,
    int gB,
    const int* __restrict__ src, const int* __restrict__ tgt,
    const int* __restrict__ posin, const int* __restrict__ rowptr,
    int* __restrict__ csrc, int E) {
  if (blockIdx.x < gB) {
    ngemm_body<128, false, 2>(Xv, WnT, Y0, Y1, N, blockIdx.x);
  } else {
    int e = (blockIdx.x - gB) * 256 + threadIdx.x;
    if (e >= E) return;
    csrc[rowptr[tgt[e]] + posin[e]] = src[e];
  }
}

// ---------------------------------------------------------------------------
// CSR aggregate body: H = relu(sum/deg + bias + Yr), bf16 rows, f32 accum.
__device__ __forceinline__ void agg_body(
    const unsigned short* __restrict__ Y, const int* __restrict__ rowptr,
    const int* __restrict__ csrc, const float* __restrict__ bias,
    const unsigned short* __restrict__ Yr, unsigned short* __restrict__ H,
    int N, int blk) {
  int node = (blk * 256 + threadIdx.x) >> 6;
  if (node >= N) return;
  const int lane = threadIdx.x & 63;
  const int c4 = lane & 15, rr = lane >> 4;
  int beg = rowptr[node], end = rowptr[node + 1];
  float a0 = 0.f, a1 = 0.f, a2 = 0.f, a3 = 0.f;
  float b0 = 0.f, b1 = 0.f, b2 = 0.f, b3 = 0.f;
  for (int e = beg; e < end; e += 8) {
    int e0 = e + rr, e1 = e + 4 + rr;
    if (e0 < end) {
      int s = csrc[e0];
      uint2 v = *(const uint2*)(Y + (size_t)s * 64 + c4 * 4);
      a0 += bf2f(v.x & 0xffffu); a1 += bf2f(v.x >> 16);
      a2 += bf2f(v.y & 0xffffu); a3 += bf2f(v.y >> 16);
    }
    if (e1 < end) {
      int s = csrc[e1];
      uint2 v = *(const uint2*)(Y + (size_t)s * 64 + c4 * 4);
      b0 += bf2f(v.x & 0xffffu); b1 += bf2f(v.x >> 16);
      b2 += bf2f(v.y & 0xffffu); b3 += bf2f(v.y >> 16);
    }
  }
  a0 += b0; a1 += b1; a2 += b2; a3 += b3;
#pragma unroll
  for (int msk = 16; msk <= 32; msk <<= 1) {
    a0 += __shfl_xor(a0, msk, 64);
    a1 += __shfl_xor(a1, msk, 64);
    a2 += __shfl_xor(a2, msk, 64);
    a3 += __shfl_xor(a3, msk, 64);
  }
  if (rr == 0) {
    float cdeg = (float)(end - beg);
    if (cdeg < 1.f) cdeg = 1.f;
    float inv = 1.f / cdeg;
    float4 bv = *(const float4*)(bias + c4 * 4);
    uint2 yv = *(const uint2*)(Yr + (size_t)node * 64 + c4 * 4);
    float o0 = fmaxf(a0 * inv + bv.x + bf2f(yv.x & 0xffffu), 0.f);
    float o1 = fmaxf(a1 * inv + bv.y + bf2f(yv.x >> 16), 0.f);
    float o2 = fmaxf(a2 * inv + bv.z + bf2f(yv.y & 0xffffu), 0.f);
    float o3 = fmaxf(a3 * inv + bv.w + bf2f(yv.y >> 16), 0.f);
    uint2 pk;
    pk.x = (unsigned int)f2bf(o0) | ((unsigned int)f2bf(o1) << 16);
    pk.y = (unsigned int)f2bf(o2) | ((unsigned int)f2bf(o3) << 16);
    *(uint2*)(H + (size_t)node * 64 + c4 * 4) = pk;
  }
}

__global__ __launch_bounds__(256) void k_agg(
    const unsigned short* __restrict__ Y, const int* __restrict__ rowptr,
    const int* __restrict__ csrc, const float* __restrict__ bias,
    const unsigned short* __restrict__ Yr, unsigned short* __restrict__ H,
    int N) {
  agg_body(Y, rowptr, csrc, bias, Yr, H, N, blockIdx.x);
}

// Agg layer-0 blocks + eattr f32->bf16 conversion blocks (independent
// streams of work; conversion hides under agg's gather latency).
__global__ __launch_bounds__(256) void k_aggc(
    const unsigned short* __restrict__ Y, const int* __restrict__ rowptr,
    const int* __restrict__ csrc, const float* __restrict__ bias,
    const unsigned short* __restrict__ Yr, unsigned short* __restrict__ H,
    int N, int aggB,
    const float4* __restrict__ ef, uint2* __restrict__ eb, int nItems,
    int nConvThreads) {
  if (blockIdx.x < aggB) {
    agg_body(Y, rowptr, csrc, bias, Yr, H, N, blockIdx.x);
  } else {
    int gid = (blockIdx.x - aggB) * 256 + threadIdx.x;
    for (int i = gid; i < nItems; i += nConvThreads) {
      float4 v = ef[i];
      uint2 pk;
      pk.x = (unsigned int)f2bf(v.x) | ((unsigned int)f2bf(v.y) << 16);
      pk.y = (unsigned int)f2bf(v.z) | ((unsigned int)f2bf(v.w) << 16);
      eb[i] = pk;
    }
  }
}

// ---------------------------------------------------------------------------
// MFMA edge pipeline v3 (unchanged from R11): bf16 EA single-load A-frag,
// coalesced G row gathers, per-wave LDS C-layout redistribution.
#define T1_STRIDE 72
#define G_STRIDE 68
__global__ __launch_bounds__(256) void k_edge3(
    const unsigned short* __restrict__ EAb, const int* __restrict__ src,
    const int* __restrict__ tgt, const unsigned short* __restrict__ Gb,
    const unsigned short* __restrict__ We1T,
    const unsigned short* __restrict__ W25T,
    const float* __restrict__ cvec, const float* __restrict__ be1,
    const float* __restrict__ Wo2, const float* __restrict__ bo2,
    float* __restrict__ out, int E, int nT, int nWaves) {
  __shared__ unsigned short sT1a[4][16 * T1_STRIDE];
  __shared__ float sGa[4][16 * G_STRIDE];
  const int tid = threadIdx.x;
  const int wid = tid >> 6, lane = tid & 63;
  const int m = lane & 15, q = lane >> 4;
  unsigned short* sT1 = sT1a[wid];
  float* sG = sGa[wid];

  short8 bWe1[4], bW25[4][2];
  float cv[4], wo2v[4], be1v[4];
#pragma unroll
  for (int nt = 0; nt < 4; ++nt) {
    int n = nt * 16 + m;
    bWe1[nt] = *(const short8*)(We1T + n * 32 + q * 8);
    bW25[nt][0] = *(const short8*)(W25T + n * 64 + q * 8);
    bW25[nt][1] = *(const short8*)(W25T + n * 64 + 32 + q * 8);
    cv[nt] = cvec[n];
    wo2v[nt] = Wo2[n];
    be1v[nt] = be1[n];
  }
  const float b_out = bo2[0];
  const short8 zfrag = {};

  int t = blockIdx.x * 4 + wid;
  if (t >= nT) return;
  int il = t * 16 + m; if (il >= E) il = E - 1;
  int my_idx = (lane < 16) ? src[il] : ((lane < 32) ? tgt[il] : 0);

  while (true) {
    const int base = t * 16;
    const int tn = t + nWaves;
    const bool last = (tn >= nT);
    const int tc = last ? t : tn;

    int il_n = tc * 16 + m; if (il_n >= E) il_n = E - 1;
    int idx_n = (lane < 16) ? src[il_n] : ((lane < 32) ? tgt[il_n] : 0);

    int rs[4], rt[4];
#pragma unroll
    for (int r = 0; r < 4; ++r) {
      rs[r] = __shfl(my_idx, q * 4 + r, 64);
      rt[r] = __shfl(my_idx, 16 + q * 4 + r, 64);
    }
    uint2 sv[4], tv[4];
#pragma unroll
    for (int r = 0; r < 4; ++r) {
      sv[r] = *(const uint2*)(Gb + (size_t)rs[r] * 64 + m * 4);
      tv[r] = *(const uint2*)(Gb + (size_t)rt[r] * 64 + m * 4);
    }

    int er = base + m; if (er >= E) er = E - 1;
    short8 aEA = zfrag;
    if (q < 2) aEA = *(const short8*)(EAb + (size_t)er * 16 + (q & 1) * 8);

    f32x4 t1[4];
#pragma unroll
    for (int nt = 0; nt < 4; ++nt) {
      f32x4 cinit; cinit[0] = be1v[nt]; cinit[1] = be1v[nt];
      cinit[2] = be1v[nt]; cinit[3] = be1v[nt];
      t1[nt] = __builtin_amdgcn_mfma_f32_16x16x32_bf16(aEA, bWe1[nt], cinit, 0, 0, 0);
    }
#pragma unroll
    for (int nt = 0; nt < 4; ++nt)
#pragma unroll
      for (int r = 0; r < 4; ++r)
        sT1[(q * 4 + r) * T1_STRIDE + nt * 16 + m] = f2bf(fmaxf(t1[nt][r], 0.f));
    short8 aT0 = *(short8*)(sT1 + m * T1_STRIDE + q * 8);
    short8 aT1 = *(short8*)(sT1 + m * T1_STRIDE + 32 + q * 8);

#pragma unroll
    for (int r = 0; r < 4; ++r) {
      f32x4 g;
      g[0] = bf2f(sv[r].x & 0xffffu) + bf2f(tv[r].x & 0xffffu);
      g[1] = bf2f(sv[r].x >> 16)     + bf2f(tv[r].x >> 16);
      g[2] = bf2f(sv[r].y & 0xffffu) + bf2f(tv[r].y & 0xffffu);
      g[3] = bf2f(sv[r].y >> 16)     + bf2f(tv[r].y >> 16);
      *(f32x4*)(sG + (q * 4 + r) * G_STRIDE + m * 4) = g;
    }

    f32x4 acc[4];
#pragma unroll
    for (int nt = 0; nt < 4; ++nt)
#pragma unroll
      for (int r = 0; r < 4; ++r)
        acc[nt][r] = cv[nt] + sG[(q * 4 + r) * G_STRIDE + nt * 16 + m];
#pragma unroll
    for (int nt = 0; nt < 4; ++nt) {
      acc[nt] = __builtin_amdgcn_mfma_f32_16x16x32_bf16(aT0, bW25[nt][0], acc[nt], 0, 0, 0);
      acc[nt] = __builtin_amdgcn_mfma_f32_16x16x32_bf16(aT1, bW25[nt][1], acc[nt], 0, 0, 0);
    }

    float p[4];
#pragma unroll
    for (int r = 0; r < 4; ++r) {
      p[r] = fmaxf(acc[0][r], 0.f) * wo2v[0] + fmaxf(acc[1][r], 0.f) * wo2v[1] +
             fmaxf(acc[2][r], 0.f) * wo2v[2] + fmaxf(acc[3][r], 0.f) * wo2v[3];
    }
#pragma unroll
    for (int msk = 1; msk <= 8; msk <<= 1) {
#pragma unroll
      for (int r = 0; r < 4; ++r) p[r] += __shfl_xor(p[r], msk, 64);
    }
    if (m == 0) {
#pragma unroll
      for (int r = 0; r < 4; ++r) {
        int row = base + q * 4 + r;
        if (row < E) out[row] = 1.f / (1.f + __expf(-(p[r] + b_out)));
      }
    }

    if (last) break;
    t = tn; my_idx = idx_n;
  }
}

// ---------------------------------------------------------------------------
extern "C" void kernel_launch(void* const* d_in, const int* in_sizes, int n_in,
                              void* d_out, int out_size, void* d_ws, size_t ws_size,
                              hipStream_t stream) {
  const float* x     = (const float*)d_in[0];
  const unsigned int* eidx = (const unsigned int*)d_in[1];
  const float* eattr = (const float*)d_in[2];
  const float* We1 = (const float*)d_in[3];
  const float* be1 = (const float*)d_in[4];
  const float* We2 = (const float*)d_in[5];
  const float* be2 = (const float*)d_in[6];
  const float* Wl0 = (const float*)d_in[7];
  const float* bl0 = (const float*)d_in[8];
  const float* Wr0 = (const float*)d_in[9];
  const float* Wl1 = (const float*)d_in[10];
  const float* bl1 = (const float*)d_in[11];
  const float* Wr1 = (const float*)d_in[12];
  const float* Wo1 = (const float*)d_in[13];
  const float* bo1 = (const float*)d_in[14];
  const float* Wo2 = (const float*)d_in[15];
  const float* bo2 = (const float*)d_in[16];

  const int N = in_sizes[0] / 128;   // 100000
  const int E = in_sizes[2] / 16;    // 1000000
  const int padN = (N + 2047) & ~2047;
  const int nB = padN / 2048;
  float* out = (float*)d_out;

  char* ws = (char*)d_ws;
  size_t off = 0;
  auto alloc = [&](size_t bytes) {
    char* p = ws + off;
    off += (bytes + 255) & ~(size_t)255;
    return p;
  };
  unsigned int* flag = (unsigned int*)alloc(256);
  int* src    = (int*)alloc((size_t)E * 4);
  int* tgt    = (int*)alloc((size_t)E * 4);
  int* posin  = (int*)alloc((size_t)E * 4);
  int* deg    = (int*)alloc((size_t)padN * 4);
  int* rowptr = (int*)alloc((size_t)(padN + 64) * 4);
  int* bsum   = (int*)alloc(64 * 4);
  int* boff   = (int*)alloc(64 * 4);
  int* csrc   = (int*)alloc((size_t)E * 4);
  unsigned short* EAb = (unsigned short*)alloc((size_t)E * 16 * 2);
  unsigned short* Hb = (unsigned short*)alloc((size_t)N * 64 * 2);
  unsigned short* Yl = (unsigned short*)alloc((size_t)N * 64 * 2);
  unsigned short* Yr = (unsigned short*)alloc((size_t)N * 64 * 2);
  unsigned short* Gb = (unsigned short*)alloc((size_t)N * 64 * 2);
  unsigned short* W25T = (unsigned short*)alloc(64 * 64 * 2);
  unsigned short* We1T = (unsigned short*)alloc(64 * 32 * 2);
  unsigned short* Wo1T = (unsigned short*)alloc(64 * 64 * 2);
  unsigned short* WnT0 = (unsigned short*)alloc(128 * 128 * 2);
  unsigned short* WnT1 = (unsigned short*)alloc(128 * 64 * 2);
  float* cvec = (float*)alloc(64 * 4);
  (void)ws_size; (void)n_in; (void)out_size;

  k_flag<<<64, 256, 0, stream>>>(eidx, 8192, flag, deg, padN);

  // MEGA1: decode + weight prep
  const int nDec = (E + 255) / 256;
  k_mega1<<<nDec + 97, 256, 0, stream>>>(
      eidx, flag, E, nDec, src, tgt, posin, deg,
      We2, Wo1, be2, bo1, We1, Wl0, Wr0, Wl1, Wr1,
      W25T, We1T, Wo1T, cvec, WnT0, WnT1);

  k_scan1<<<nB, 256, 0, stream>>>(deg, bsum);
  k_scan2<<<1, 64, 0, stream>>>(bsum, boff, nB);
  k_scan3<<<nB, 256, 0, stream>>>(deg, boff, rowptr);

  // MEGA2: layer-0 GEMM + atomic-free CSR fill
  const int gB = (N + 63) / 64;
  k_mega2<<<gB + nDec, 256, 0, stream>>>(x, WnT0, Yl, Yr, N, gB,
                                         src, tgt, posin, rowptr, csrc, E);

  // agg layer 0 + eattr bf16 conversion
  const int aggB = (N + 3) / 4;
  const int convB = 2048;
  k_aggc<<<aggB + convB, 256, 0, stream>>>(Yl, rowptr, csrc, bl0, Yr, Hb, N,
                                           aggB, (const float4*)eattr,
                                           (uint2*)EAb, E * 4, convB * 256);

  // Layer 1
  k_ngemm<64, true, 2><<<gB, 256, 0, stream>>>(Hb, WnT1, Yl, Yr, N);
  k_agg<<<aggB, 256, 0, stream>>>(Yl, rowptr, csrc, bl1, Yr, Hb, N);

  // G = H2 @ Wo1
  k_ngemm<64, true, 1><<<gB, 256, 0, stream>>>(Hb, Wo1T, Gb, nullptr, N);

  // MFMA edge pipeline v3
  const int nT = (E + 15) / 16;
  const int blocks = 3072;
  k_edge3<<<blocks, 256, 0, stream>>>(EAb, src, tgt, Gb, We1T, W25T, cvec,
                                      be1, Wo2, bo2, out, E, nT, blocks * 4);
}

// Round 13
// 412.794 us; speedup vs baseline: 1.1057x; 1.0808x over previous
//
#include <hip/hip_runtime.h>
#include <math.h>

typedef __attribute__((ext_vector_type(8))) short short8;
typedef __attribute__((ext_vector_type(4))) float f32x4;

static __device__ __forceinline__ unsigned short f2bf(float f) {
  union { float f; unsigned int u; } x; x.f = f;
  unsigned int r = x.u + 0x7fffu + ((x.u >> 16) & 1u);  // RNE
  return (unsigned short)(r >> 16);
}
static __device__ __forceinline__ float bf2f(unsigned int u) {
  union { unsigned int u; float f; } x; x.u = u << 16; return x.f;
}

// ---------------------------------------------------------------------------
// Block 0: int64-vs-int32 edge_index detection. ALL blocks: zero deg[padN].
__global__ void k_flag(const unsigned int* __restrict__ w, int nSample,
                       unsigned int* __restrict__ flag,
                       int* __restrict__ deg, int padN) {
  int4* d4 = (int4*)deg;
  int n4 = padN >> 2;
  for (int i = blockIdx.x * 256 + threadIdx.x; i < n4; i += gridDim.x * 256)
    d4[i] = make_int4(0, 0, 0, 0);
  if (blockIdx.x != 0) return;
  __shared__ unsigned int red[256];
  unsigned int v = 0;
  for (int i = threadIdx.x; i < nSample; i += 256) v |= w[2 * i + 1];
  red[threadIdx.x] = v;
  __syncthreads();
  for (int s = 128; s > 0; s >>= 1) {
    if (threadIdx.x < s) red[threadIdx.x] |= red[threadIdx.x + s];
    __syncthreads();
  }
  if (threadIdx.x == 0) flag[0] = red[0];  // nonzero => int32 layout
}

// ---------------------------------------------------------------------------
// MFMA node GEMM body. INLINEW: build B fragments directly from f32 W0/W1
// (no dependency on prep blocks -> safe to co-dispatch in one mega kernel).
// MFMA layouts (gfx950, verified): A[m=lane&15][k=(lane>>4)*8+j],
// B[k][n=lane&15], C/D col=lane&15, row=(lane>>4)*4+reg.
template <int K, bool BF16IN, int NTILES, bool INLINEW>
__device__ __forceinline__ void ngemm_body(
    const void* __restrict__ Xv, const unsigned short* __restrict__ WnT,
    const float* __restrict__ W0f, const float* __restrict__ W1f,
    unsigned short* __restrict__ Y0, unsigned short* __restrict__ Y1,
    int N, int blk, unsigned short* __restrict__ sX) {
  constexpr int STR = K + 8;
  constexpr int NC = K / 32;
  const int tid = threadIdx.x;
  const int wv = tid >> 6, lane = tid & 63;
  const int m = lane & 15, q = lane >> 4;
  const int row0 = blk * 64;

  short8 bB[NTILES][NC];
#pragma unroll
  for (int ct = 0; ct < NTILES; ++ct)
#pragma unroll
    for (int c = 0; c < NC; ++c) {
      if constexpr (INLINEW) {
        int n = (NTILES == 2) ? (wv * 32 + ct * 16 + m) : (wv * 16 + m);
        const float* Wf = (n < 64) ? W0f : W1f;
        int nn = n & 63;
        union { short8 s; unsigned short h[8]; } ub;
#pragma unroll
        for (int j = 0; j < 8; ++j)
          ub.h[j] = f2bf(Wf[(size_t)(c * 32 + q * 8 + j) * 64 + nn]);
        bB[ct][c] = ub.s;
      } else {
        int n = (NTILES == 2) ? (wv * 32 + ct * 16 + m) : (wv * 16 + m);
        bB[ct][c] = *(const short8*)(WnT + (size_t)n * K + c * 32 + q * 8);
      }
    }

#pragma unroll
  for (int i = 0; i < K / 16; ++i) {
    int f = tid + 256 * i;
    int r = f / (K / 4);
    int c4 = f % (K / 4);
    int rr = row0 + r; if (rr >= N) rr = N - 1;
    uint2 pk;
    if constexpr (BF16IN) {
      pk = *(const uint2*)((const unsigned short*)Xv + (size_t)rr * K + c4 * 4);
    } else {
      float4 v = *(const float4*)((const float*)Xv + (size_t)rr * K + c4 * 4);
      pk.x = (unsigned int)f2bf(v.x) | ((unsigned int)f2bf(v.y) << 16);
      pk.y = (unsigned int)f2bf(v.z) | ((unsigned int)f2bf(v.w) << 16);
    }
    *(uint2*)(sX + r * STR + c4 * 4) = pk;
  }
  __syncthreads();

  f32x4 acc[4][NTILES];
#pragma unroll
  for (int rt = 0; rt < 4; ++rt)
#pragma unroll
    for (int ct = 0; ct < NTILES; ++ct)
#pragma unroll
      for (int r = 0; r < 4; ++r) acc[rt][ct][r] = 0.f;

#pragma unroll
  for (int c = 0; c < NC; ++c) {
    short8 a[4];
#pragma unroll
    for (int rt = 0; rt < 4; ++rt)
      a[rt] = *(const short8*)(sX + (rt * 16 + m) * STR + c * 32 + q * 8);
#pragma unroll
    for (int rt = 0; rt < 4; ++rt)
#pragma unroll
      for (int ct = 0; ct < NTILES; ++ct)
        acc[rt][ct] = __builtin_amdgcn_mfma_f32_16x16x32_bf16(a[rt], bB[ct][c], acc[rt][ct], 0, 0, 0);
  }

#pragma unroll
  for (int rt = 0; rt < 4; ++rt)
#pragma unroll
    for (int ct = 0; ct < NTILES; ++ct) {
      unsigned short* Yw;
      int n;
      if constexpr (NTILES == 2) {
        Yw = (wv < 2) ? Y0 : Y1;
        n = (wv & 1) * 32 + ct * 16 + m;
      } else {
        Yw = Y0;
        n = wv * 16 + m;
      }
#pragma unroll
      for (int reg = 0; reg < 4; ++reg) {
        int row = row0 + rt * 16 + q * 4 + reg;
        if (row < N) Yw[(size_t)row * 64 + n] = f2bf(acc[rt][ct][reg]);
      }
    }
}

template <int K, bool BF16IN, int NTILES>
__global__ __launch_bounds__(256) void k_ngemm(
    const void* __restrict__ Xv, const unsigned short* __restrict__ WnT,
    unsigned short* __restrict__ Y0, unsigned short* __restrict__ Y1, int N) {
  __shared__ __align__(16) unsigned short sX[64 * (K + 8)];
  ngemm_body<K, BF16IN, NTILES, false>(Xv, WnT, nullptr, nullptr, Y0, Y1, N,
                                       blockIdx.x, sX);
}

// ---------------------------------------------------------------------------
// MEGA1: pack decode's ~75us atomic-fabric shadow with ALL independent work:
//   decode blocks       : src/tgt/rank + degree (atomic-return bound)
//   prep block          : W25T/We1T/Wo1T/cvec (LDS)
//   WnT1 blocks         : layer-1 weight transpose->bf16
//   ngemm128 blocks     : Yl|Yr = x @ [Wl0|Wr0]  (INLINE f32 weights - no
//                         dependency on prep blocks; avoids intra-kernel race)
//   conv blocks         : eattr f32 -> bf16
// Proportional striping of blockIdx so compute blocks co-reside with decode
// blocks from t=0 (R11 lesson: latency hides extra work only across WAVES).
__global__ __launch_bounds__(256) void k_mega1(
    const unsigned int* __restrict__ w, const unsigned int* __restrict__ flag,
    int E, int nDec, int nWork, int gB, int nConvThreads,
    int* __restrict__ src, int* __restrict__ tgt,
    int* __restrict__ posin, int* __restrict__ deg,
    const float* __restrict__ x, unsigned short* __restrict__ Yl,
    unsigned short* __restrict__ Yr, int N,
    const float* __restrict__ We2, const float* __restrict__ Wo1,
    const float* __restrict__ be2, const float* __restrict__ bo1,
    const float* __restrict__ We1,
    const float* __restrict__ Wl0, const float* __restrict__ Wr0,
    const float* __restrict__ Wl1, const float* __restrict__ Wr1,
    unsigned short* __restrict__ W25T, unsigned short* __restrict__ We1T,
    unsigned short* __restrict__ Wo1T, float* __restrict__ cvec,
    unsigned short* __restrict__ WnT1,
    const float4* __restrict__ ef, uint2* __restrict__ eb) {
  __shared__ __align__(16) char smem[64 * 136 * 2];   // 17408 B, union use
  const int tid = threadIdx.x;
  const int tot = nDec + nWork;
  // proportional striping: decode-count before this block
  const int di  = (int)(((long long)blockIdx.x * nDec) / tot);
  const int di1 = (int)(((long long)(blockIdx.x + 1) * nDec) / tot);

  if (di1 > di) {
    // ---- decode block #di
    int e = di * 256 + tid;
    if (e >= E) return;
    int s, t;
    if (flag[0]) { s = (int)w[e]; t = (int)w[E + e]; }
    else         { s = (int)w[2 * e]; t = (int)w[2 * (E + e)]; }
    src[e] = s;
    tgt[e] = t;
    posin[e] = atomicAdd(deg + t, 1);
    return;
  }
  const int wi = blockIdx.x - di;
  if (wi == 0) {
    // ---- prep: W25T=(We2@Wo1)^T, Wo1T, We1T, cvec (Wo1 staged in smem)
    float* sB = (float*)smem;
    for (int i = tid; i < 1024; i += 256)
      *(float4*)&sB[i * 4] = *(const float4*)(Wo1 + i * 4);
    __syncthreads();
    for (int idx = tid; idx < 4096; idx += 256) {
      int k = idx >> 6, n = idx & 63;   // k wave-uniform -> We2 scalarizes
      float s = 0.f;
#pragma unroll 8
      for (int mm = 0; mm < 64; ++mm) s = fmaf(We2[k * 64 + mm], sB[mm * 64 + n], s);
      W25T[n * 64 + k] = f2bf(s);
      Wo1T[n * 64 + k] = f2bf(sB[k * 64 + n]);
    }
    for (int idx = tid; idx < 2048; idx += 256) {
      int n = idx >> 5, k = idx & 31;
      We1T[n * 32 + k] = (k < 16) ? f2bf(We1[k * 64 + n]) : (unsigned short)0;
    }
    if (tid < 64) {
      float s = bo1[tid];
#pragma unroll 8
      for (int mm = 0; mm < 64; ++mm) s = fmaf(be2[mm], sB[mm * 64 + tid], s);
      cvec[tid] = s;
    }
  } else if (wi <= 32) {
    // ---- WnT1 transpose (128x64)
    int idx = (wi - 1) * 256 + tid;
    int n = idx >> 6, k = idx & 63;
    float v = (n < 64) ? Wl1[(size_t)k * 64 + n] : Wr1[(size_t)k * 64 + (n - 64)];
    WnT1[idx] = f2bf(v);
  } else if (wi < 33 + gB) {
    // ---- layer-0 GEMM (inline f32 weights)
    ngemm_body<128, false, 2, true>(x, nullptr, Wl0, Wr0, Yl, Yr, N,
                                    wi - 33, (unsigned short*)smem);
  } else {
    // ---- eattr f32 -> bf16
    int gid = (wi - 33 - gB) * 256 + tid;
    int nItems = E * 4;
    for (int i = gid; i < nItems; i += nConvThreads) {
      float4 v = ef[i];
      uint2 pk;
      pk.x = (unsigned int)f2bf(v.x) | ((unsigned int)f2bf(v.y) << 16);
      pk.y = (unsigned int)f2bf(v.z) | ((unsigned int)f2bf(v.w) << 16);
      eb[i] = pk;
    }
  }
}

// ---------------------------------------------------------------------------
// Hierarchical exclusive scan of deg[padN] (padN multiple of 2048, pad=0).
__global__ __launch_bounds__(256) void k_scan1(const int* __restrict__ deg,
                                               int* __restrict__ bsum) {
  __shared__ int wsum[4];
  const int tid = threadIdx.x, lane = tid & 63, wid = tid >> 6;
  const int base = blockIdx.x * 2048 + tid * 8;
  int4 v0 = *(const int4*)(deg + base);
  int4 v1 = *(const int4*)(deg + base + 4);
  int s = v0.x + v0.y + v0.z + v0.w + v1.x + v1.y + v1.z + v1.w;
#pragma unroll
  for (int off = 1; off < 64; off <<= 1) s += __shfl_xor(s, off, 64);
  if (lane == 0) wsum[wid] = s;
  __syncthreads();
  if (tid == 0) bsum[blockIdx.x] = wsum[0] + wsum[1] + wsum[2] + wsum[3];
}

__global__ void k_scan2(const int* __restrict__ bsum, int* __restrict__ boff,
                        int nB) {
  int lane = threadIdx.x;
  int v = (lane < nB) ? bsum[lane] : 0;
  int incl = v;
#pragma unroll
  for (int off = 1; off < 64; off <<= 1) {
    int t = __shfl_up(incl, off, 64);
    if (lane >= off) incl += t;
  }
  if (lane < nB) boff[lane] = incl - v;
}

__global__ __launch_bounds__(256) void k_scan3(const int* __restrict__ deg,
                                               const int* __restrict__ boff,
                                               int* __restrict__ rowptr) {
  __shared__ int wsum[4];
  const int tid = threadIdx.x, lane = tid & 63, wid = tid >> 6;
  const int base = blockIdx.x * 2048 + tid * 8;
  int4 v0 = *(const int4*)(deg + base);
  int4 v1 = *(const int4*)(deg + base + 4);
  int e[8] = {v0.x, v0.y, v0.z, v0.w, v1.x, v1.y, v1.z, v1.w};
  int s = e[0] + e[1] + e[2] + e[3] + e[4] + e[5] + e[6] + e[7];
  int incl = s;
#pragma unroll
  for (int off = 1; off < 64; off <<= 1) {
    int t = __shfl_up(incl, off, 64);
    if (lane >= off) incl += t;
  }
  if (lane == 63) wsum[wid] = incl;
  __syncthreads();
  int run = boff[blockIdx.x] + (incl - s);
  for (int w = 0; w < wid; ++w) run += wsum[w];
  int o[8];
#pragma unroll
  for (int i = 0; i < 8; ++i) { o[i] = run; run += e[i]; }
  *(int4*)(rowptr + base) = make_int4(o[0], o[1], o[2], o[3]);
  *(int4*)(rowptr + base + 4) = make_int4(o[4], o[5], o[6], o[7]);
}

// Atomic-free CSR fill: position precomputed as rowptr[tgt] + rank.
__global__ void k_fill(const int* __restrict__ src, const int* __restrict__ tgt,
                       const int* __restrict__ posin,
                       const int* __restrict__ rowptr,
                       int* __restrict__ csrc, int E) {
  int e = blockIdx.x * 256 + threadIdx.x;
  if (e >= E) return;
  csrc[rowptr[tgt[e]] + posin[e]] = src[e];
}

// ---------------------------------------------------------------------------
// CSR aggregate: H = relu(sum/deg + bias + Yr), bf16 rows, f32 accum.
__global__ __launch_bounds__(256) void k_agg(
    const unsigned short* __restrict__ Y, const int* __restrict__ rowptr,
    const int* __restrict__ csrc, const float* __restrict__ bias,
    const unsigned short* __restrict__ Yr, unsigned short* __restrict__ H,
    int N) {
  int node = (blockIdx.x * 256 + threadIdx.x) >> 6;
  if (node >= N) return;
  const int lane = threadIdx.x & 63;
  const int c4 = lane & 15, rr = lane >> 4;
  int beg = rowptr[node], end = rowptr[node + 1];
  float a0 = 0.f, a1 = 0.f, a2 = 0.f, a3 = 0.f;
  float b0 = 0.f, b1 = 0.f, b2 = 0.f, b3 = 0.f;
  for (int e = beg; e < end; e += 8) {
    int e0 = e + rr, e1 = e + 4 + rr;
    if (e0 < end) {
      int s = csrc[e0];
      uint2 v = *(const uint2*)(Y + (size_t)s * 64 + c4 * 4);
      a0 += bf2f(v.x & 0xffffu); a1 += bf2f(v.x >> 16);
      a2 += bf2f(v.y & 0xffffu); a3 += bf2f(v.y >> 16);
    }
    if (e1 < end) {
      int s = csrc[e1];
      uint2 v = *(const uint2*)(Y + (size_t)s * 64 + c4 * 4);
      b0 += bf2f(v.x & 0xffffu); b1 += bf2f(v.x >> 16);
      b2 += bf2f(v.y & 0xffffu); b3 += bf2f(v.y >> 16);
    }
  }
  a0 += b0; a1 += b1; a2 += b2; a3 += b3;
#pragma unroll
  for (int msk = 16; msk <= 32; msk <<= 1) {
    a0 += __shfl_xor(a0, msk, 64);
    a1 += __shfl_xor(a1, msk, 64);
    a2 += __shfl_xor(a2, msk, 64);
    a3 += __shfl_xor(a3, msk, 64);
  }
  if (rr == 0) {
    float cdeg = (float)(end - beg);
    if (cdeg < 1.f) cdeg = 1.f;
    float inv = 1.f / cdeg;
    float4 bv = *(const float4*)(bias + c4 * 4);
    uint2 yv = *(const uint2*)(Yr + (size_t)node * 64 + c4 * 4);
    float o0 = fmaxf(a0 * inv + bv.x + bf2f(yv.x & 0xffffu), 0.f);
    float o1 = fmaxf(a1 * inv + bv.y + bf2f(yv.x >> 16), 0.f);
    float o2 = fmaxf(a2 * inv + bv.z + bf2f(yv.y & 0xffffu), 0.f);
    float o3 = fmaxf(a3 * inv + bv.w + bf2f(yv.y >> 16), 0.f);
    uint2 pk;
    pk.x = (unsigned int)f2bf(o0) | ((unsigned int)f2bf(o1) << 16);
    pk.y = (unsigned int)f2bf(o2) | ((unsigned int)f2bf(o3) << 16);
    *(uint2*)(H + (size_t)node * 64 + c4 * 4) = pk;
  }
}

// ---------------------------------------------------------------------------
// MFMA edge pipeline v3 (unchanged): bf16 EA single-load A-frag, coalesced
// G row gathers, per-wave LDS C-layout redistribution.
#define T1_STRIDE 72
#define G_STRIDE 68
__global__ __launch_bounds__(256) void k_edge3(
    const unsigned short* __restrict__ EAb, const int* __restrict__ src,
    const int* __restrict__ tgt, const unsigned short* __restrict__ Gb,
    const unsigned short* __restrict__ We1T,
    const unsigned short* __restrict__ W25T,
    const float* __restrict__ cvec, const float* __restrict__ be1,
    const float* __restrict__ Wo2, const float* __restrict__ bo2,
    float* __restrict__ out, int E, int nT, int nWaves) {
  __shared__ unsigned short sT1a[4][16 * T1_STRIDE];
  __shared__ float sGa[4][16 * G_STRIDE];
  const int tid = threadIdx.x;
  const int wid = tid >> 6, lane = tid & 63;
  const int m = lane & 15, q = lane >> 4;
  unsigned short* sT1 = sT1a[wid];
  float* sG = sGa[wid];

  short8 bWe1[4], bW25[4][2];
  float cv[4], wo2v[4], be1v[4];
#pragma unroll
  for (int nt = 0; nt < 4; ++nt) {
    int n = nt * 16 + m;
    bWe1[nt] = *(const short8*)(We1T + n * 32 + q * 8);
    bW25[nt][0] = *(const short8*)(W25T + n * 64 + q * 8);
    bW25[nt][1] = *(const short8*)(W25T + n * 64 + 32 + q * 8);
    cv[nt] = cvec[n];
    wo2v[nt] = Wo2[n];
    be1v[nt] = be1[n];
  }
  const float b_out = bo2[0];
  const short8 zfrag = {};

  int t = blockIdx.x * 4 + wid;
  if (t >= nT) return;
  int il = t * 16 + m; if (il >= E) il = E - 1;
  int my_idx = (lane < 16) ? src[il] : ((lane < 32) ? tgt[il] : 0);

  while (true) {
    const int base = t * 16;
    const int tn = t + nWaves;
    const bool last = (tn >= nT);
    const int tc = last ? t : tn;

    int il_n = tc * 16 + m; if (il_n >= E) il_n = E - 1;
    int idx_n = (lane < 16) ? src[il_n] : ((lane < 32) ? tgt[il_n] : 0);

    int rs[4], rt[4];
#pragma unroll
    for (int r = 0; r < 4; ++r) {
      rs[r] = __shfl(my_idx, q * 4 + r, 64);
      rt[r] = __shfl(my_idx, 16 + q * 4 + r, 64);
    }
    uint2 sv[4], tv[4];
#pragma unroll
    for (int r = 0; r < 4; ++r) {
      sv[r] = *(const uint2*)(Gb + (size_t)rs[r] * 64 + m * 4);
      tv[r] = *(const uint2*)(Gb + (size_t)rt[r] * 64 + m * 4);
    }

    int er = base + m; if (er >= E) er = E - 1;
    short8 aEA = zfrag;
    if (q < 2) aEA = *(const short8*)(EAb + (size_t)er * 16 + (q & 1) * 8);

    f32x4 t1[4];
#pragma unroll
    for (int nt = 0; nt < 4; ++nt) {
      f32x4 cinit; cinit[0] = be1v[nt]; cinit[1] = be1v[nt];
      cinit[2] = be1v[nt]; cinit[3] = be1v[nt];
      t1[nt] = __builtin_amdgcn_mfma_f32_16x16x32_bf16(aEA, bWe1[nt], cinit, 0, 0, 0);
    }
#pragma unroll
    for (int nt = 0; nt < 4; ++nt)
#pragma unroll
      for (int r = 0; r < 4; ++r)
        sT1[(q * 4 + r) * T1_STRIDE + nt * 16 + m] = f2bf(fmaxf(t1[nt][r], 0.f));
    short8 aT0 = *(short8*)(sT1 + m * T1_STRIDE + q * 8);
    short8 aT1 = *(short8*)(sT1 + m * T1_STRIDE + 32 + q * 8);

#pragma unroll
    for (int r = 0; r < 4; ++r) {
      f32x4 g;
      g[0] = bf2f(sv[r].x & 0xffffu) + bf2f(tv[r].x & 0xffffu);
      g[1] = bf2f(sv[r].x >> 16)     + bf2f(tv[r].x >> 16);
      g[2] = bf2f(sv[r].y & 0xffffu) + bf2f(tv[r].y & 0xffffu);
      g[3] = bf2f(sv[r].y >> 16)     + bf2f(tv[r].y >> 16);
      *(f32x4*)(sG + (q * 4 + r) * G_STRIDE + m * 4) = g;
    }

    f32x4 acc[4];
#pragma unroll
    for (int nt = 0; nt < 4; ++nt)
#pragma unroll
      for (int r = 0; r < 4; ++r)
        acc[nt][r] = cv[nt] + sG[(q * 4 + r) * G_STRIDE + nt * 16 + m];
#pragma unroll
    for (int nt = 0; nt < 4; ++nt) {
      acc[nt] = __builtin_amdgcn_mfma_f32_16x16x32_bf16(aT0, bW25[nt][0], acc[nt], 0, 0, 0);
      acc[nt] = __builtin_amdgcn_mfma_f32_16x16x32_bf16(aT1, bW25[nt][1], acc[nt], 0, 0, 0);
    }

    float p[4];
#pragma unroll
    for (int r = 0; r < 4; ++r) {
      p[r] = fmaxf(acc[0][r], 0.f) * wo2v[0] + fmaxf(acc[1][r], 0.f) * wo2v[1] +
             fmaxf(acc[2][r], 0.f) * wo2v[2] + fmaxf(acc[3][r], 0.f) * wo2v[3];
    }
#pragma unroll
    for (int msk = 1; msk <= 8; msk <<= 1) {
#pragma unroll
      for (int r = 0; r < 4; ++r) p[r] += __shfl_xor(p[r], msk, 64);
    }
    if (m == 0) {
#pragma unroll
      for (int r = 0; r < 4; ++r) {
        int row = base + q * 4 + r;
        if (row < E) out[row] = 1.f / (1.f + __expf(-(p[r] + b_out)));
      }
    }

    if (last) break;
    t = tn; my_idx = idx_n;
  }
}

// ---------------------------------------------------------------------------
extern "C" void kernel_launch(void* const* d_in, const int* in_sizes, int n_in,
                              void* d_out, int out_size, void* d_ws, size_t ws_size,
                              hipStream_t stream) {
  const float* x     = (const float*)d_in[0];
  const unsigned int* eidx = (const unsigned int*)d_in[1];
  const float* eattr = (const float*)d_in[2];
  const float* We1 = (const float*)d_in[3];
  const float* be1 = (const float*)d_in[4];
  const float* We2 = (const float*)d_in[5];
  const float* be2 = (const float*)d_in[6];
  const float* Wl0 = (const float*)d_in[7];
  const float* bl0 = (const float*)d_in[8];
  const float* Wr0 = (const float*)d_in[9];
  const float* Wl1 = (const float*)d_in[10];
  const float* bl1 = (const float*)d_in[11];
  const float* Wr1 = (const float*)d_in[12];
  const float* Wo1 = (const float*)d_in[13];
  const float* bo1 = (const float*)d_in[14];
  const float* Wo2 = (const float*)d_in[15];
  const float* bo2 = (const float*)d_in[16];

  const int N = in_sizes[0] / 128;   // 100000
  const int E = in_sizes[2] / 16;    // 1000000
  const int padN = (N + 2047) & ~2047;
  const int nB = padN / 2048;
  float* out = (float*)d_out;

  char* ws = (char*)d_ws;
  size_t off = 0;
  auto alloc = [&](size_t bytes) {
    char* p = ws + off;
    off += (bytes + 255) & ~(size_t)255;
    return p;
  };
  unsigned int* flag = (unsigned int*)alloc(256);
  int* src    = (int*)alloc((size_t)E * 4);
  int* tgt    = (int*)alloc((size_t)E * 4);
  int* posin  = (int*)alloc((size_t)E * 4);
  int* deg    = (int*)alloc((size_t)padN * 4);
  int* rowptr = (int*)alloc((size_t)(padN + 64) * 4);
  int* bsum   = (int*)alloc(64 * 4);
  int* boff   = (int*)alloc(64 * 4);
  int* csrc   = (int*)alloc((size_t)E * 4);
  unsigned short* EAb = (unsigned short*)alloc((size_t)E * 16 * 2);
  unsigned short* Hb = (unsigned short*)alloc((size_t)N * 64 * 2);
  unsigned short* Yl = (unsigned short*)alloc((size_t)N * 64 * 2);
  unsigned short* Yr = (unsigned short*)alloc((size_t)N * 64 * 2);
  unsigned short* Gb = (unsigned short*)alloc((size_t)N * 64 * 2);
  unsigned short* W25T = (unsigned short*)alloc(64 * 64 * 2);
  unsigned short* We1T = (unsigned short*)alloc(64 * 32 * 2);
  unsigned short* Wo1T = (unsigned short*)alloc(64 * 64 * 2);
  unsigned short* WnT1 = (unsigned short*)alloc(128 * 64 * 2);
  float* cvec = (float*)alloc(64 * 4);
  (void)ws_size; (void)n_in; (void)out_size;

  k_flag<<<64, 256, 0, stream>>>(eidx, 8192, flag, deg, padN);

  // MEGA1: decode + prep + WnT1 + layer-0 GEMM (inline weights) + eattr conv
  const int nDec = (E + 255) / 256;
  const int gB = (N + 63) / 64;
  const int convB = 1024;
  const int nWork = 33 + gB + convB;
  k_mega1<<<nDec + nWork, 256, 0, stream>>>(
      eidx, flag, E, nDec, nWork, gB, convB * 256,
      src, tgt, posin, deg,
      x, Yl, Yr, N,
      We2, Wo1, be2, bo1, We1, Wl0, Wr0, Wl1, Wr1,
      W25T, We1T, Wo1T, cvec, WnT1,
      (const float4*)eattr, (uint2*)EAb);

  k_scan1<<<nB, 256, 0, stream>>>(deg, bsum);
  k_scan2<<<1, 64, 0, stream>>>(bsum, boff, nB);
  k_scan3<<<nB, 256, 0, stream>>>(deg, boff, rowptr);
  k_fill<<<nDec, 256, 0, stream>>>(src, tgt, posin, rowptr, csrc, E);

  const int aggB = (N + 3) / 4;
  k_agg<<<aggB, 256, 0, stream>>>(Yl, rowptr, csrc, bl0, Yr, Hb, N);

  // Layer 1
  k_ngemm<64, true, 2><<<gB, 256, 0, stream>>>(Hb, WnT1, Yl, Yr, N);
  k_agg<<<aggB, 256, 0, stream>>>(Yl, rowptr, csrc, bl1, Yr, Hb, N);

  // G = H2 @ Wo1
  k_ngemm<64, true, 1><<<gB, 256, 0, stream>>>(Hb, Wo1T, Gb, nullptr, N);

  // MFMA edge pipeline v3
  const int nT = (E + 15) / 16;
  const int blocks = 3072;
  k_edge3<<<blocks, 256, 0, stream>>>(EAb, src, tgt, Gb, We1T, W25T, cvec,
                                      be1, Wo2, bo2, out, E, nT, blocks * 4);
}